// Round 1
// baseline (273.051 us; speedup 1.0000x reference)
//
#include <hip/hip_runtime.h>
#include <climits>

typedef __attribute__((ext_vector_type(8))) short s8;      // 8 bf16 = 4 VGPRs
typedef __attribute__((ext_vector_type(4))) float f32x4;   // MFMA acc

#define BQ    256
#define DDIM  256
#define NBANK 100000
#define BN    64                          // bank cols per block (4 col-tiles of 16)
#define NJB   ((NBANK + BN - 1) / BN)     // 1563
#define SENT  1e30f

// Split fp32 x into bf16 hi (round-half-up) + bf16 lo: x ~= hi + lo, |err| <~ 2^-18|x|
__device__ inline void splitElem(float x, s8& h, s8& l, int i) {
    unsigned u  = __float_as_uint(x);
    unsigned uh = (u + 0x8000u) & 0xFFFF0000u;
    h[i] = (short)(uh >> 16);
    float lf = x - __uint_as_float(uh);            // exact
    l[i] = (short)((__float_as_uint(lf) + 0x8000u) >> 16);
}

__device__ inline void split8(const float4 v0, const float4 v1, s8& h, s8& l) {
    splitElem(v0.x, h, l, 0); splitElem(v0.y, h, l, 1);
    splitElem(v0.z, h, l, 2); splitElem(v0.w, h, l, 3);
    splitElem(v1.x, h, l, 4); splitElem(v1.y, h, l, 5);
    splitElem(v1.z, h, l, 6); splitElem(v1.w, h, l, 7);
}

__device__ inline float sq8(const float4 v0, const float4 v1, float s) {
    s = fmaf(v0.x, v0.x, s); s = fmaf(v0.y, v0.y, s);
    s = fmaf(v0.z, v0.z, s); s = fmaf(v0.w, v0.w, s);
    s = fmaf(v1.x, v1.x, s); s = fmaf(v1.y, v1.y, s);
    s = fmaf(v1.z, v1.z, s); s = fmaf(v1.w, v1.w, s);
    return s;
}

// Kernel 0: pre-split the tiny A (feature) into MFMA-A-fragment-ordered bf16 hi/lo.
// Frag t = (rowtile rt)*8 + ks, lane l holds feature[rt*16+(l&15)][ks*32+(l>>4)*8 + 0..7].
__global__ __launch_bounds__(512) void split_feature(
    const float* __restrict__ feature, s8* __restrict__ fH, s8* __restrict__ fL)
{
    const int t    = blockIdx.x * 512 + threadIdx.x;   // 0..8191
    const int lane = t & 63, ks = (t >> 6) & 7, rt = t >> 9;
    const int row  = rt * 16 + (lane & 15);
    const int k0   = ks * 32 + (lane >> 4) * 8;
    const float* p = feature + (size_t)row * DDIM + k0;
    const float4 v0 = *(const float4*)p;
    const float4 v1 = *(const float4*)(p + 4);
    s8 h, l;
    split8(v0, v1, h, l);
    fH[t] = h; fL[t] = l;
}

// Kernel 1: full-K-staged split-bf16 MFMA GEMM + fused masked partial argmin.
// The WHOLE 64-col x 256-k B tile (hi+lo) is staged in 64 KB of LDS in ONE pass,
// so there are exactly 2 barriers per block and the 512-MFMA compute loop runs
// with no barrier-forced vmcnt(0) drains. 2 blocks/CU co-resident (134 KB LDS)
// -> one block's staging hides under the other's MFMA burst.
__global__ __launch_bounds__(256, 2) void gemm_argmin_fullk(
    const s8* __restrict__ fH, const s8* __restrict__ fL,
    const float* __restrict__ bank,
    const int* __restrict__ cluster_label, const int* __restrict__ class_label,
    const int* __restrict__ cluster_idx,  const int* __restrict__ gt_label,
    float* __restrict__ wsPV, int* __restrict__ wsPI,
    float* __restrict__ wsDV, int* __restrict__ wsDI)
{
    __shared__ __align__(16) s8 bHs[8 * 4 * 64];   // [s][ct][lane] 32 KB
    __shared__ __align__(16) s8 bLs[8 * 4 * 64];   // 32 KB
    __shared__ float b2s[BN];
    __shared__ int clsS[BN], cluS[BN], rowGt[BQ], rowClu[BQ];

    const int tid = threadIdx.x;
    const int jb  = blockIdx.x;
    const int j0  = jb * BN;

    if (tid < BN) {
        int jg = j0 + tid;
        int jc = jg < NBANK ? jg : NBANK - 1;
        clsS[tid] = class_label[jc];
        cluS[tid] = cluster_label[jc];
    }
    rowGt[tid]  = gt_label[tid];
    rowClu[tid] = cluster_idx[tid];

    // ---- Staging: thread -> (col = tid>>2, q = tid&3); stages k-octet q of all 8 slices
    const int col = tid >> 2, q = tid & 3;
    const int ct_s = col >> 4, cl_s = col & 15;
    int jcol = j0 + col; jcol = jcol < NBANK ? jcol : NBANK - 1;
    const float* gb = bank + (size_t)jcol * DDIM + q * 8;

    // Issue all 16 global loads up-front so latency is paid once, not 8x.
    float4 v0[8], v1[8];
    #pragma unroll
    for (int s = 0; s < 8; ++s) {
        v0[s] = *(const float4*)(gb + s * 32);
        v1[s] = *(const float4*)(gb + s * 32 + 4);
    }
    float sqa = 0.f;
    #pragma unroll
    for (int s = 0; s < 8; ++s) {
        s8 h, l;
        split8(v0[s], v1[s], h, l);
        sqa = sq8(v0[s], v1[s], sqa);
        const int wi = (s * 4 + ct_s) * 64 + q * 16 + cl_s;   // frag-lane slot
        bHs[wi] = h;
        bLs[wi] = l;
    }
    // ||b||^2: the 4 q-threads of each col are adjacent lanes
    sqa += __shfl_xor(sqa, 1);
    sqa += __shfl_xor(sqa, 2);
    if (q == 0) b2s[col] = sqa;
    __syncthreads();                       // staging visible; the ONLY mid-kernel barrier

    // ---- Compute: wave w owns rows w*64..+63 (4 row-tiles); 512 MFMAs, no barriers
    const int w = tid >> 6, lane = tid & 63;
    const int g = lane >> 4, c = lane & 15;

    f32x4 acc[4][4];
    #pragma unroll
    for (int ct = 0; ct < 4; ++ct)
        #pragma unroll
        for (int rt = 0; rt < 4; ++rt)
            acc[ct][rt] = (f32x4){0.f, 0.f, 0.f, 0.f};

    #pragma unroll
    for (int s = 0; s < 8; ++s) {
        s8 aH[4], aL[4];
        #pragma unroll
        for (int rt = 0; rt < 4; ++rt) {   // A frags from L2-resident fH/fL
            const int RT = w * 4 + rt;
            aH[rt] = fH[(RT * 8 + s) * 64 + lane];
            aL[rt] = fL[(RT * 8 + s) * 64 + lane];
        }
        #pragma unroll
        for (int ct = 0; ct < 4; ++ct) {
            const s8 bh = bHs[(s * 4 + ct) * 64 + lane];
            const s8 bl = bLs[(s * 4 + ct) * 64 + lane];
            #pragma unroll
            for (int rt = 0; rt < 4; ++rt) {
                acc[ct][rt] = __builtin_amdgcn_mfma_f32_16x16x32_bf16(aH[rt], bh, acc[ct][rt], 0, 0, 0);
                acc[ct][rt] = __builtin_amdgcn_mfma_f32_16x16x32_bf16(aH[rt], bl, acc[ct][rt], 0, 0, 0);
                acc[ct][rt] = __builtin_amdgcn_mfma_f32_16x16x32_bf16(aL[rt], bh, acc[ct][rt], 0, 0, 0);
                acc[ct][rt] = __builtin_amdgcn_mfma_f32_16x16x32_bf16(aL[rt], bl, acc[ct][rt], 0, 0, 0);
            }
        }
    }

    // ---- Epilogue: C/D layout col = lane&15, row = g*4 + reg (HW-verified, absmax 0)
    #pragma unroll
    for (int rt = 0; rt < 4; ++rt) {
        #pragma unroll
        for (int r = 0; r < 4; ++r) {
            const int row  = w * 64 + rt * 16 + g * 4 + r;
            const int myGt = rowGt[row], myClu = rowClu[row];
            float bpv = SENT, bdv = SENT;
            int   bpi = INT_MAX, bdi = INT_MAX;
            #pragma unroll
            for (int ct = 0; ct < 4; ++ct) {   // ascending ct = ascending col per lane
                const int jg = j0 + ct * 16 + c;
                const float sc = b2s[ct * 16 + c] - 2.f * acc[ct][rt][r];
                if (jg < NBANK && clsS[ct * 16 + c] != myGt) {
                    if (sc < bdv) { bdv = sc; bdi = jg; }
                    if (cluS[ct * 16 + c] == myClu && sc < bpv) { bpv = sc; bpi = jg; }
                }
            }
            #pragma unroll
            for (int off = 1; off < 16; off <<= 1) {   // tie-aware 16-lane reduce
                float vv = __shfl_xor(bpv, off); int ii = __shfl_xor(bpi, off);
                if (vv < bpv || (vv == bpv && ii < bpi)) { bpv = vv; bpi = ii; }
                vv = __shfl_xor(bdv, off); ii = __shfl_xor(bdi, off);
                if (vv < bdv || (vv == bdv && ii < bdi)) { bdv = vv; bdi = ii; }
            }
            if (c == 0) {
                // TRANSPOSED partial layout [jb][row]: block writes a contiguous
                // 1 KB run per array -> ~6.4 MB HBM writes instead of ~50 MB RMW.
                const size_t o = (size_t)jb * BQ + row;
                wsPV[o] = bpv; wsPI[o] = bpi;
                wsDV[o] = bdv; wsDI[o] = bdi;
            }
        }
    }
}

// Kernel 2: per-row reduction over NJB partials (transposed layout), fallback
// select, gather bank row.
__global__ __launch_bounds__(256) void reduce_gather(
    const float* __restrict__ wsPV, const int* __restrict__ wsPI,
    const float* __restrict__ wsDV, const int* __restrict__ wsDI,
    const float* __restrict__ bank, float* __restrict__ out)
{
    const int row = blockIdx.x, tid = threadIdx.x;
    float bpv = SENT, bdv = SENT;
    int   bpi = INT_MAX, bdi = INT_MAX;
    for (int b = tid; b < NJB; b += 256) {
        const size_t o = (size_t)b * BQ + row;
        float v = wsPV[o]; int ix = wsPI[o];
        if (v < bpv || (v == bpv && ix < bpi)) { bpv = v; bpi = ix; }
        v = wsDV[o]; ix = wsDI[o];
        if (v < bdv || (v == bdv && ix < bdi)) { bdv = v; bdi = ix; }
    }
    #pragma unroll
    for (int off = 32; off > 0; off >>= 1) {
        float v = __shfl_down(bpv, off); int ix = __shfl_down(bpi, off);
        if (v < bpv || (v == bpv && ix < bpi)) { bpv = v; bpi = ix; }
        v = __shfl_down(bdv, off); ix = __shfl_down(bdi, off);
        if (v < bdv || (v == bdv && ix < bdi)) { bdv = v; bdi = ix; }
    }
    __shared__ float swPV[4], swDV[4];
    __shared__ int   swPI[4], swDI[4];
    __shared__ int   sIdx;
    const int lane = tid & 63, wv = tid >> 6;
    if (lane == 0) { swPV[wv] = bpv; swPI[wv] = bpi; swDV[wv] = bdv; swDI[wv] = bdi; }
    __syncthreads();
    if (tid == 0) {
        float pv = swPV[0]; int pi = swPI[0];
        float dv = swDV[0]; int di = swDI[0];
        #pragma unroll
        for (int w = 1; w < 4; ++w) {
            if (swPV[w] < pv || (swPV[w] == pv && swPI[w] < pi)) { pv = swPV[w]; pi = swPI[w]; }
            if (swDV[w] < dv || (swDV[w] == dv && swDI[w] < di)) { dv = swDV[w]; di = swDI[w]; }
        }
        sIdx = (pi != INT_MAX) ? pi : ((di != INT_MAX) ? di : 0);
    }
    __syncthreads();
    out[row * DDIM + tid] = bank[(size_t)sIdx * DDIM + tid];
}

extern "C" void kernel_launch(void* const* d_in, const int* in_sizes, int n_in,
                              void* d_out, int out_size, void* d_ws, size_t ws_size,
                              hipStream_t stream) {
    const float* feature       = (const float*)d_in[0];
    const float* bank          = (const float*)d_in[1];
    const int*   cluster_label = (const int*)d_in[2];
    const int*   class_label   = (const int*)d_in[3];
    const int*   cluster_idx   = (const int*)d_in[4];
    const int*   gt_label      = (const int*)d_in[5];
    float* out = (float*)d_out;

    // Workspace: fH/fL (128 KB each) + 4 partial arrays [NJB][256] (6.4 MB) = 6.66 MB
    s8* fH = (s8*)d_ws;                 // 8192 frags
    s8* fL = fH + 8192;
    float* base = (float*)((char*)d_ws + 2 * 8192 * sizeof(s8));
    const size_t per = (size_t)BQ * NJB;
    float* wsPV = base;
    int*   wsPI = (int*)base + per;
    float* wsDV = base + 2 * per;
    int*   wsDI = (int*)base + 3 * per;

    hipLaunchKernelGGL(split_feature, dim3(16), dim3(512), 0, stream, feature, fH, fL);
    hipLaunchKernelGGL(gemm_argmin_fullk, dim3(NJB), dim3(256), 0, stream,
                       fH, fL, bank, cluster_label, class_label, cluster_idx, gt_label,
                       wsPV, wsPI, wsDV, wsDI);
    hipLaunchKernelGGL(reduce_gather, dim3(BQ), dim3(256), 0, stream,
                       wsPV, wsPI, wsDV, wsDI, bank, out);
}

// Round 2
// 240.967 us; speedup vs baseline: 1.1331x; 1.1331x over previous
//
#include <hip/hip_runtime.h>
#include <climits>

typedef __attribute__((ext_vector_type(8))) short s8;      // 8 bf16 = 4 VGPRs
typedef __attribute__((ext_vector_type(4))) float f32x4;   // MFMA acc

#define BQ    256
#define DDIM  256
#define NBANK 100000
#define BN    64                          // bank cols per block (4 col-tiles of 16)
#define NJB   ((NBANK + BN - 1) / BN)     // 1563
#define SENT  1e30f

// Split fp32 x into bf16 hi (round-half-up) + bf16 lo: x ~= hi + lo, |err| <~ 2^-18|x|
__device__ inline void splitElem(float x, s8& h, s8& l, int i) {
    unsigned u  = __float_as_uint(x);
    unsigned uh = (u + 0x8000u) & 0xFFFF0000u;
    h[i] = (short)(uh >> 16);
    float lf = x - __uint_as_float(uh);            // exact
    l[i] = (short)((__float_as_uint(lf) + 0x8000u) >> 16);
}

__device__ inline void split8(const float4 v0, const float4 v1, s8& h, s8& l) {
    splitElem(v0.x, h, l, 0); splitElem(v0.y, h, l, 1);
    splitElem(v0.z, h, l, 2); splitElem(v0.w, h, l, 3);
    splitElem(v1.x, h, l, 4); splitElem(v1.y, h, l, 5);
    splitElem(v1.z, h, l, 6); splitElem(v1.w, h, l, 7);
}

__device__ inline float sq8(const float4 v0, const float4 v1, float s) {
    s = fmaf(v0.x, v0.x, s); s = fmaf(v0.y, v0.y, s);
    s = fmaf(v0.z, v0.z, s); s = fmaf(v0.w, v0.w, s);
    s = fmaf(v1.x, v1.x, s); s = fmaf(v1.y, v1.y, s);
    s = fmaf(v1.z, v1.z, s); s = fmaf(v1.w, v1.w, s);
    return s;
}

// Kernel 0: pre-split the tiny A (feature) into MFMA-A-fragment-ordered bf16 hi/lo.
// Frag t = (rowtile rt)*8 + ks, lane l holds feature[rt*16+(l&15)][ks*32+(l>>4)*8 + 0..7].
__global__ __launch_bounds__(512) void split_feature(
    const float* __restrict__ feature, s8* __restrict__ fH, s8* __restrict__ fL)
{
    const int t    = blockIdx.x * 512 + threadIdx.x;   // 0..8191
    const int lane = t & 63, ks = (t >> 6) & 7, rt = t >> 9;
    const int row  = rt * 16 + (lane & 15);
    const int k0   = ks * 32 + (lane >> 4) * 8;
    const float* p = feature + (size_t)row * DDIM + k0;
    const float4 v0 = *(const float4*)p;
    const float4 v1 = *(const float4*)(p + 4);
    s8 h, l;
    split8(v0, v1, h, l);
    fH[t] = h; fL[t] = l;
}

// Kernel 1: full-K-staged split-bf16 MFMA GEMM + fused masked partial argmin.
// OCCUPANCY-FIRST restructure: 512 threads = 8 waves/block, each wave owns
// 32 rows (2 row-tiles) -> acc halves to 32 AGPRs, total regs fit 4 waves/SIMD.
// LDS 68 KB -> 2 blocks/CU co-resident -> 16 waves/CU (~50% occ) vs 18.6%.
// Latency-bound regime (MfmaUtil 14%, HBM 5%): dur should scale ~1/occupancy.
__global__ __launch_bounds__(512, 4) void gemm_argmin_fullk(
    const s8* __restrict__ fH, const s8* __restrict__ fL,
    const float* __restrict__ bank,
    const int* __restrict__ cluster_label, const int* __restrict__ class_label,
    const int* __restrict__ cluster_idx,  const int* __restrict__ gt_label,
    float* __restrict__ wsPV, int* __restrict__ wsPI,
    float* __restrict__ wsDV, int* __restrict__ wsDI)
{
    __shared__ __align__(16) s8 bHs[8 * 4 * 64];   // [s][ct][fraglane] 32 KB
    __shared__ __align__(16) s8 bLs[8 * 4 * 64];   // 32 KB
    __shared__ float b2s[BN];
    __shared__ int clsS[BN], cluS[BN], rowGt[BQ], rowClu[BQ];

    const int tid = threadIdx.x;
    const int jb  = blockIdx.x;
    const int j0  = jb * BN;

    if (tid < BN) {
        int jg = j0 + tid;
        int jc = jg < NBANK ? jg : NBANK - 1;
        clsS[tid] = class_label[jc];
        cluS[tid] = cluster_label[jc];
    }
    if (tid < BQ) {
        rowGt[tid]  = gt_label[tid];
        rowClu[tid] = cluster_idx[tid];
    }

    // ---- Staging: thread (col = tid>>3, q = tid&7) stages slice s=q of its col:
    // 4 k-octets (128 B contiguous global read), split to bf16 hi/lo frags in LDS.
    const int col = tid >> 3, q = tid & 7;
    const int ct_s = col >> 4, cl_s = col & 15;
    int jcol = j0 + col; jcol = jcol < NBANK ? jcol : NBANK - 1;
    const float* gb = bank + (size_t)jcol * DDIM + q * 32;

    float4 v0[4], v1[4];
    #pragma unroll
    for (int i = 0; i < 4; ++i) {
        v0[i] = *(const float4*)(gb + i * 8);
        v1[i] = *(const float4*)(gb + i * 8 + 4);
    }
    float sqa = 0.f;
    #pragma unroll
    for (int i = 0; i < 4; ++i) {
        s8 h, l;
        split8(v0[i], v1[i], h, l);
        sqa = sq8(v0[i], v1[i], sqa);
        const int wi = (q * 4 + ct_s) * 64 + i * 16 + cl_s;   // frag-lane slot
        bHs[wi] = h;
        bLs[wi] = l;
    }
    // ||b||^2: the 8 q-threads of each col are adjacent lanes (tid&7)
    sqa += __shfl_xor(sqa, 1);
    sqa += __shfl_xor(sqa, 2);
    sqa += __shfl_xor(sqa, 4);
    if (q == 0) b2s[col] = sqa;
    __syncthreads();                       // staging visible; the ONLY mid-kernel barrier

    // ---- Compute: wave w (0..7) owns rows w*32..+31 (2 row-tiles); 256 MFMAs/wave
    const int w = tid >> 6, lane = tid & 63;
    const int g = lane >> 4, c = lane & 15;

    f32x4 acc[4][2];
    #pragma unroll
    for (int ct = 0; ct < 4; ++ct)
        #pragma unroll
        for (int rt = 0; rt < 2; ++rt)
            acc[ct][rt] = (f32x4){0.f, 0.f, 0.f, 0.f};

    #pragma unroll
    for (int s = 0; s < 8; ++s) {
        s8 aH[2], aL[2];
        #pragma unroll
        for (int rt = 0; rt < 2; ++rt) {   // A frags from L2-resident fH/fL
            const int RT = w * 2 + rt;
            aH[rt] = fH[(RT * 8 + s) * 64 + lane];
            aL[rt] = fL[(RT * 8 + s) * 64 + lane];
        }
        #pragma unroll
        for (int ct = 0; ct < 4; ++ct) {
            const s8 bh = bHs[(s * 4 + ct) * 64 + lane];
            const s8 bl = bLs[(s * 4 + ct) * 64 + lane];
            #pragma unroll
            for (int rt = 0; rt < 2; ++rt) {
                acc[ct][rt] = __builtin_amdgcn_mfma_f32_16x16x32_bf16(aH[rt], bh, acc[ct][rt], 0, 0, 0);
                acc[ct][rt] = __builtin_amdgcn_mfma_f32_16x16x32_bf16(aH[rt], bl, acc[ct][rt], 0, 0, 0);
                acc[ct][rt] = __builtin_amdgcn_mfma_f32_16x16x32_bf16(aL[rt], bh, acc[ct][rt], 0, 0, 0);
                acc[ct][rt] = __builtin_amdgcn_mfma_f32_16x16x32_bf16(aL[rt], bl, acc[ct][rt], 0, 0, 0);
            }
        }
    }

    // ---- Epilogue: C/D layout col = lane&15, row = g*4 + reg (HW-verified, absmax 0)
    #pragma unroll
    for (int rt = 0; rt < 2; ++rt) {
        #pragma unroll
        for (int r = 0; r < 4; ++r) {
            const int row  = w * 32 + rt * 16 + g * 4 + r;
            const int myGt = rowGt[row], myClu = rowClu[row];
            float bpv = SENT, bdv = SENT;
            int   bpi = INT_MAX, bdi = INT_MAX;
            #pragma unroll
            for (int ct = 0; ct < 4; ++ct) {   // ascending ct = ascending col per lane
                const int jg = j0 + ct * 16 + c;
                const float sc = b2s[ct * 16 + c] - 2.f * acc[ct][rt][r];
                if (jg < NBANK && clsS[ct * 16 + c] != myGt) {
                    if (sc < bdv) { bdv = sc; bdi = jg; }
                    if (cluS[ct * 16 + c] == myClu && sc < bpv) { bpv = sc; bpi = jg; }
                }
            }
            #pragma unroll
            for (int off = 1; off < 16; off <<= 1) {   // tie-aware 16-lane reduce
                float vv = __shfl_xor(bpv, off); int ii = __shfl_xor(bpi, off);
                if (vv < bpv || (vv == bpv && ii < bpi)) { bpv = vv; bpi = ii; }
                vv = __shfl_xor(bdv, off); ii = __shfl_xor(bdi, off);
                if (vv < bdv || (vv == bdv && ii < bdi)) { bdv = vv; bdi = ii; }
            }
            if (c == 0) {
                // Transposed partial layout [jb][row]: contiguous 1 KB runs per
                // array -> ~6.4 MB HBM writes (verified round 1: 50 -> 6.3 MB).
                const size_t o = (size_t)jb * BQ + row;
                wsPV[o] = bpv; wsPI[o] = bpi;
                wsDV[o] = bdv; wsDI[o] = bdi;
            }
        }
    }
}

// Kernel 2: per-row reduction over NJB partials (transposed layout), fallback
// select, gather bank row.
__global__ __launch_bounds__(256) void reduce_gather(
    const float* __restrict__ wsPV, const int* __restrict__ wsPI,
    const float* __restrict__ wsDV, const int* __restrict__ wsDI,
    const float* __restrict__ bank, float* __restrict__ out)
{
    const int row = blockIdx.x, tid = threadIdx.x;
    float bpv = SENT, bdv = SENT;
    int   bpi = INT_MAX, bdi = INT_MAX;
    for (int b = tid; b < NJB; b += 256) {
        const size_t o = (size_t)b * BQ + row;
        float v = wsPV[o]; int ix = wsPI[o];
        if (v < bpv || (v == bpv && ix < bpi)) { bpv = v; bpi = ix; }
        v = wsDV[o]; ix = wsDI[o];
        if (v < bdv || (v == bdv && ix < bdi)) { bdv = v; bdi = ix; }
    }
    #pragma unroll
    for (int off = 32; off > 0; off >>= 1) {
        float v = __shfl_down(bpv, off); int ix = __shfl_down(bpi, off);
        if (v < bpv || (v == bpv && ix < bpi)) { bpv = v; bpi = ix; }
        v = __shfl_down(bdv, off); ix = __shfl_down(bdi, off);
        if (v < bdv || (v == bdv && ix < bdi)) { bdv = v; bdi = ix; }
    }
    __shared__ float swPV[4], swDV[4];
    __shared__ int   swPI[4], swDI[4];
    __shared__ int   sIdx;
    const int lane = tid & 63, wv = tid >> 6;
    if (lane == 0) { swPV[wv] = bpv; swPI[wv] = bpi; swDV[wv] = bdv; swDI[wv] = bdi; }
    __syncthreads();
    if (tid == 0) {
        float pv = swPV[0]; int pi = swPI[0];
        float dv = swDV[0]; int di = swDI[0];
        #pragma unroll
        for (int w = 1; w < 4; ++w) {
            if (swPV[w] < pv || (swPV[w] == pv && swPI[w] < pi)) { pv = swPV[w]; pi = swPI[w]; }
            if (swDV[w] < dv || (swDV[w] == dv && swDI[w] < di)) { dv = swDV[w]; di = swDI[w]; }
        }
        sIdx = (pi != INT_MAX) ? pi : ((di != INT_MAX) ? di : 0);
    }
    __syncthreads();
    out[row * DDIM + tid] = bank[(size_t)sIdx * DDIM + tid];
}

extern "C" void kernel_launch(void* const* d_in, const int* in_sizes, int n_in,
                              void* d_out, int out_size, void* d_ws, size_t ws_size,
                              hipStream_t stream) {
    const float* feature       = (const float*)d_in[0];
    const float* bank          = (const float*)d_in[1];
    const int*   cluster_label = (const int*)d_in[2];
    const int*   class_label   = (const int*)d_in[3];
    const int*   cluster_idx   = (const int*)d_in[4];
    const int*   gt_label      = (const int*)d_in[5];
    float* out = (float*)d_out;

    // Workspace: fH/fL (128 KB each) + 4 partial arrays [NJB][256] (6.4 MB) = 6.66 MB
    s8* fH = (s8*)d_ws;                 // 8192 frags
    s8* fL = fH + 8192;
    float* base = (float*)((char*)d_ws + 2 * 8192 * sizeof(s8));
    const size_t per = (size_t)BQ * NJB;
    float* wsPV = base;
    int*   wsPI = (int*)base + per;
    float* wsDV = base + 2 * per;
    int*   wsDI = (int*)base + 3 * per;

    hipLaunchKernelGGL(split_feature, dim3(16), dim3(512), 0, stream, feature, fH, fL);
    hipLaunchKernelGGL(gemm_argmin_fullk, dim3(NJB), dim3(512), 0, stream,
                       fH, fL, bank, cluster_label, class_label, cluster_idx, gt_label,
                       wsPV, wsPI, wsDV, wsDI);
    hipLaunchKernelGGL(reduce_gather, dim3(BQ), dim3(256), 0, stream,
                       wsPV, wsPI, wsDV, wsDI, bank, out);
}